// Round 11
// baseline (65.097 us; speedup 1.0000x reference)
//
#include <hip/hip_runtime.h>
#include <hip/hip_bf16.h>

// Problem constants
#define BATCH   4096
#define NF      128    // n features == n models
#define NA      16
#define IN_DIM  144    // N_FEATURES + N_ACTIONS
#define KP      160    // w1t K padded to multiple of 32 (col 144 carries b1)
#define KF      192    // fab K padded so row = 384 B (XOR-swizzle closed)
#define HID     256

typedef __attribute__((ext_vector_type(8))) short bf16x8;
typedef __attribute__((ext_vector_type(4))) float f32x4;
typedef unsigned int u32;

// async global->LDS, 16B per lane. LDS dest must be wave-uniform base + lane*16.
__device__ __forceinline__ void gl_lds16(const void* gsrc, void* ldst) {
    __builtin_amdgcn_global_load_lds(
        (const __attribute__((address_space(1))) u32*)gsrc,
        (__attribute__((address_space(3))) u32*)ldst, 16, 0, 0);
}

// ---------------------------------------------------------------------------
// Merged convert kernel:
//   blocks [0, 1280):      W1 [128][144][256] fp32 -> w1t [128][256][160] bf16
//                          (transposed, col 144 := b1 -> GEMM adds bias)
//   blocks [1280, 1664):   fa = concat(f_t, a_t, 1.0, 0pad) -> bf16 [4096][192],
//                          pre-swizzled: chunk cc stored at cc ^ (row&7)
__global__ void convert_all(const float* __restrict__ W1,
                            const float* __restrict__ b1,
                            const float* __restrict__ f_t,
                            const float* __restrict__ a_t,
                            __hip_bfloat16* __restrict__ w1t,
                            __hip_bfloat16* __restrict__ fab) {
    const int bid = blockIdx.x;
    const int t = threadIdx.x;
    if (bid < 1280) {
        __shared__ float tile[16][HID];
        int m = bid / 10;
        int kc = bid - m * 10;
        int k0 = kc * 16;
        if (kc < 9) {
#pragma unroll
            for (int i = 0; i < 16; ++i)
                tile[i][t] = W1[((size_t)m * IN_DIM + (k0 + i)) * HID + t];
            __syncthreads();
            union { ushort us[16]; uint4 q[2]; } pk;
#pragma unroll
            for (int i = 0; i < 16; ++i) {
                __hip_bfloat16 h = __float2bfloat16(tile[i][t]);
                pk.us[i] = *(ushort*)&h;
            }
            uint4* dst = (uint4*)(w1t + ((size_t)m * HID + t) * KP + k0);
            dst[0] = pk.q[0];
            dst[1] = pk.q[1];
        } else {
            // pad region k = 144..159: k=144 carries b1, rest zero.
            union { ushort us[8]; uint4 q; } pk;
#pragma unroll
            for (int j = 0; j < 8; ++j) pk.us[j] = 0;
            __hip_bfloat16 hb = __float2bfloat16(b1[(size_t)m * HID + t]);
            pk.us[0] = *(ushort*)&hb;
            uint4 z = {0u, 0u, 0u, 0u};
            uint4* dst = (uint4*)(w1t + ((size_t)m * HID + t) * KP + IN_DIM);
            dst[0] = pk.q;
            dst[1] = z;
        }
    } else {
        int c = (bid - 1280) * 256 + t;
        const int total = BATCH * (KF / 8);   // 24 chunks per row
        if (c >= total) return;
        int row = c / 24;
        int cc = c - row * 24;
        union { ushort us[8]; uint4 q; } pk;
#pragma unroll
        for (int j = 0; j < 8; ++j) {
            int k = cc * 8 + j;
            float v;
            if (k < NF)            v = f_t[(size_t)row * NF + k];
            else if (k < IN_DIM)   v = a_t[(size_t)row * NA + (k - NF)];
            else if (k == IN_DIM)  v = 1.0f;   // bias lane
            else                   v = 0.0f;
            __hip_bfloat16 h = __float2bfloat16(v);
            pk.us[j] = *(ushort*)&h;
        }
        int pc = cc ^ (row & 7);              // bijective within 24 chunks
        *(uint4*)(fab + (size_t)row * KF + pc * 8) = pk.q;
    }
}

// ---------------------------------------------------------------------------
// Fused grouped MLP — counted-vmcnt triple-buffer pipeline (T3/T4 style).
// Grid 1024 = 128 m (bid&127) x 8 slices; 16 tiles of 32 rows per block.
// 256 thr = 4 waves; wave w owns hid cols [w*64, w*64+64).
// Role split: waves 1-3 stage (exactly 4 global_load_lds per tile each ->
// s_waitcnt vmcnt(4) at top of tile t guarantees stage(t) landed while
// stage(t+1) stays in flight ACROSS the barrier). Wave 0 handles the
// deferred combine/store of tile t-1 plus the skip gather. One barrier/tile.
__global__ __launch_bounds__(256, 3) void fused_mlp(
        const __hip_bfloat16* __restrict__ fab,
        const __hip_bfloat16* __restrict__ w1t,
        const float* __restrict__ W2,
        const float* __restrict__ b2,
        const float* __restrict__ f_t,
        float* __restrict__ out) {
    __shared__ __align__(16) __hip_bfloat16 Abuf[3][32 * KF];  // 3 x 12 KB
    __shared__ __align__(16) float partial[2][4][32];          // 1 KB

    const int bid = blockIdx.x;
    const int m     = bid & 127;     // same-m blocks 128 apart -> same XCD L2
    const int slice = bid >> 7;      // 0..7, 512 rows each
    const int row_base = slice * 512;
    const int t = threadIdx.x;
    const int w = t >> 6;            // wave = hid col group 0..3 (64 cols)
    const int lane = t & 63;
    const int lrow = lane & 15;
    const int g = lane >> 4;         // 0..3
    const int xr = (lrow & 7) << 4;  // byte XOR for swizzled LDS reads

    // ---- prologue: W1T frags (MFMA A operand), W2 per-lane f32x4.
    bf16x8 bfrag[4][5];
#pragma unroll
    for (int hi = 0; hi < 4; ++hi) {
        const int col = w * 64 + hi * 16 + lrow;
        const __hip_bfloat16* wp = w1t + ((size_t)m * HID + col) * KP + g * 8;
#pragma unroll
        for (int ks = 0; ks < 5; ++ks)
            bfrag[hi][ks] = *(const bf16x8*)(wp + ks * 32);
    }
    f32x4 w2v[4];
#pragma unroll
    for (int hi = 0; hi < 4; ++hi)
        w2v[hi] = *(const f32x4*)(W2 + (size_t)m * HID + w * 64 + hi * 16 + g * 4);
    const float b2v = b2[m];
    const f32x4 zc = (f32x4){0.f, 0.f, 0.f, 0.f};

    // ---- stage tiles 0,1 (waves 1-3: 768 chunks / 192 lanes = 4 each)
    if (w >= 1) {
#pragma unroll
        for (int tt = 0; tt < 2; ++tt) {
            const char* src = (const char*)(fab + (size_t)(row_base + tt * 32) * KF);
            char* dst = (char*)&Abuf[tt][0];
#pragma unroll
            for (int i = 0; i < 4; ++i) {
                int chunk = (w - 1) * 256 + i * 64 + lane;
                gl_lds16(src + (size_t)chunk * 16, dst + chunk * 16);
            }
        }
    }

    float skip_prev = 0.0f;
    for (int tile = 0; tile < 16; ++tile) {
        const int cur = tile % 3;
        const int r0 = row_base + tile * 32;

        // ---- counted wait + barrier (never vmcnt(0) until the tail)
        if (w >= 1) {
            if (tile < 15)
                asm volatile("s_waitcnt vmcnt(4) lgkmcnt(0)\n\ts_barrier" ::: "memory");
            else
                asm volatile("s_waitcnt vmcnt(0) lgkmcnt(0)\n\ts_barrier" ::: "memory");
        } else {
            asm volatile("s_waitcnt lgkmcnt(0)\n\ts_barrier" ::: "memory");
        }

        // ---- stage tile+2 into buf[(tile+2)%3] (free: that buf was last
        // read at tile-1; all waves passed barrier since).
        if (w >= 1 && tile < 14) {
            const char* src = (const char*)(fab + (size_t)(r0 + 64) * KF);
            char* dst = (char*)&Abuf[(tile + 2) % 3][0];
#pragma unroll
            for (int i = 0; i < 4; ++i) {
                int chunk = (w - 1) * 256 + i * 64 + lane;
                gl_lds16(src + (size_t)chunk * 16, dst + chunk * 16);
            }
        }

        // ---- wave 0: deferred combine+store of tile-1; skip gather for this
        // tile (consumed at tile+1). Runs in parallel with staging & MFMA.
        float skip_cur = 0.0f;
        if (w == 0) {
            if (lane < 32) {
                if (tile >= 1) {
                    const int pb = (tile - 1) & 1;
                    float v = (partial[pb][0][lane] + partial[pb][1][lane])
                            + (partial[pb][2][lane] + partial[pb][3][lane])
                            + b2v + skip_prev;
                    out[(size_t)(r0 - 32 + lane) * NF + m] = v;
                }
                skip_cur = f_t[(size_t)(r0 + lane) * NF + m];
            }
        }
        skip_prev = skip_cur;

        // ---- compute tile: 32 rows x 256 hid, K=160
        f32x4 acc[4][2];   // [hi][bj]
        const char* ab = (const char*)&Abuf[cur][0];

        // ks = 0: C = zero vector (no per-tile acc zero-init VALU)
        {
            bf16x8 a[2];
#pragma unroll
            for (int bj = 0; bj < 2; ++bj) {
                int off = (bj * 16 + lrow) * 384 + ((g * 16) ^ xr);
                a[bj] = *(const bf16x8*)(ab + off);
            }
#pragma unroll
            for (int hi = 0; hi < 4; ++hi)
#pragma unroll
                for (int bj = 0; bj < 2; ++bj)
                    acc[hi][bj] = __builtin_amdgcn_mfma_f32_16x16x32_bf16(
                        bfrag[hi][0], a[bj], zc, 0, 0, 0);
        }
#pragma unroll
        for (int ks = 1; ks < 5; ++ks) {
            bf16x8 a[2];   // fa frag: batch = bj*16 + lrow, k = ks*32 + g*8
#pragma unroll
            for (int bj = 0; bj < 2; ++bj) {
                int off = (bj * 16 + lrow) * 384 + ((ks * 64 + g * 16) ^ xr);
                a[bj] = *(const bf16x8*)(ab + off);
            }
#pragma unroll
            for (int hi = 0; hi < 4; ++hi)
#pragma unroll
                for (int bj = 0; bj < 2; ++bj)
                    acc[hi][bj] = __builtin_amdgcn_mfma_f32_16x16x32_bf16(
                        bfrag[hi][ks], a[bj], acc[hi][bj], 0, 0, 0);
        }

        // ---- epilogue: relu(acc) * W2 (b1 folded into GEMM).
        float sarr[2];
#pragma unroll
        for (int bj = 0; bj < 2; ++bj) {
            float sr0 = 0.f, sr1 = 0.f, sr2 = 0.f, sr3 = 0.f;
#pragma unroll
            for (int hi = 0; hi < 4; ++hi) {
                float h0 = acc[hi][bj][0]; h0 = h0 > 0.f ? h0 : 0.f;
                float h1 = acc[hi][bj][1]; h1 = h1 > 0.f ? h1 : 0.f;
                float h2 = acc[hi][bj][2]; h2 = h2 > 0.f ? h2 : 0.f;
                float h3 = acc[hi][bj][3]; h3 = h3 > 0.f ? h3 : 0.f;
                sr0 = fmaf(h0, w2v[hi][0], sr0);
                sr1 = fmaf(h1, w2v[hi][1], sr1);
                sr2 = fmaf(h2, w2v[hi][2], sr2);
                sr3 = fmaf(h3, w2v[hi][3], sr3);
            }
            float s = (sr0 + sr1) + (sr2 + sr3);
            // sum the 4 g-groups (hid quarters of this wave's 64 cols)
            s += __shfl_xor(s, 16, 64);
            s += __shfl_xor(s, 32, 64);
            sarr[bj] = s;
        }
        // lanes with g<2 hold the final sums; write partial[tile&1]
        if (g < 2)
            partial[tile & 1][w][(g & 1) * 16 + lrow] = (g & 1) ? sarr[1] : sarr[0];
    }

    // ---- drain: combine tile 15
    asm volatile("s_waitcnt lgkmcnt(0)\n\ts_barrier" ::: "memory");
    if (w == 0 && lane < 32) {
        const int pb = 15 & 1;
        float v = (partial[pb][0][lane] + partial[pb][1][lane])
                + (partial[pb][2][lane] + partial[pb][3][lane])
                + b2v + skip_prev;
        out[(size_t)(row_base + 15 * 32 + lane) * NF + m] = v;
    }
}

// ---------------------------------------------------------------------------
extern "C" void kernel_launch(void* const* d_in, const int* in_sizes, int n_in,
                              void* d_out, int out_size, void* d_ws, size_t ws_size,
                              hipStream_t stream) {
    const float* f_t = (const float*)d_in[0];
    const float* a_t = (const float*)d_in[1];
    const float* W1  = (const float*)d_in[2];
    const float* b1  = (const float*)d_in[3];
    const float* W2  = (const float*)d_in[4];
    const float* b2  = (const float*)d_in[5];
    float* out = (float*)d_out;

    // ws layout: w1t bf16 [128][256][160] (10.49 MB), fab bf16 [4096][192] (1.57 MB)
    __hip_bfloat16* w1t = (__hip_bfloat16*)d_ws;
    __hip_bfloat16* fab = (__hip_bfloat16*)((char*)d_ws + (size_t)NF * HID * KP * 2);

    // converts merged: 1280 w1t blocks + 384 fa blocks
    hipLaunchKernelGGL(convert_all, dim3(1664), dim3(256), 0, stream,
                       W1, b1, f_t, a_t, w1t, fab);
    hipLaunchKernelGGL(fused_mlp, dim3(1024), dim3(256), 0, stream,
                       fab, w1t, W2, b2, f_t, out);
}

// Round 12
// 58.826 us; speedup vs baseline: 1.1066x; 1.1066x over previous
//
#include <hip/hip_runtime.h>
#include <hip/hip_bf16.h>

// Problem constants
#define BATCH   4096
#define NF      128    // n features == n models
#define NA      16
#define IN_DIM  144    // N_FEATURES + N_ACTIONS
#define KP      160    // w1t K padded (col 144 carries b1; 160 = 10 k-steps of 16)
#define KF      192    // fab K padded so row = 384 B (XOR-swizzle closed)
#define HID     256

typedef __attribute__((ext_vector_type(8))) short bf16x8;
typedef __attribute__((ext_vector_type(4))) float f32x4;
typedef __attribute__((ext_vector_type(16))) float f32x16;
typedef unsigned int u32;

// async global->LDS, 16B per lane. LDS dest must be wave-uniform base + lane*16.
__device__ __forceinline__ void gl_lds16(const void* gsrc, void* ldst) {
    __builtin_amdgcn_global_load_lds(
        (const __attribute__((address_space(1))) u32*)gsrc,
        (__attribute__((address_space(3))) u32*)ldst, 16, 0, 0);
}

// ---------------------------------------------------------------------------
// Merged convert kernel:
//   blocks [0, 1280):      W1 [128][144][256] fp32 -> w1t [128][256][160] bf16
//                          (transposed, col 144 := b1 -> GEMM adds bias)
//   blocks [1280, 1664):   fa = concat(f_t, a_t, 1.0, 0pad) -> bf16 [4096][192],
//                          pre-swizzled: chunk cc stored at cc ^ (row&7)
__global__ void convert_all(const float* __restrict__ W1,
                            const float* __restrict__ b1,
                            const float* __restrict__ f_t,
                            const float* __restrict__ a_t,
                            __hip_bfloat16* __restrict__ w1t,
                            __hip_bfloat16* __restrict__ fab) {
    const int bid = blockIdx.x;
    const int t = threadIdx.x;
    if (bid < 1280) {
        __shared__ float tile[16][HID];
        int m = bid / 10;
        int kc = bid - m * 10;
        int k0 = kc * 16;
        if (kc < 9) {
#pragma unroll
            for (int i = 0; i < 16; ++i)
                tile[i][t] = W1[((size_t)m * IN_DIM + (k0 + i)) * HID + t];
            __syncthreads();
            union { ushort us[16]; uint4 q[2]; } pk;
#pragma unroll
            for (int i = 0; i < 16; ++i) {
                __hip_bfloat16 h = __float2bfloat16(tile[i][t]);
                pk.us[i] = *(ushort*)&h;
            }
            uint4* dst = (uint4*)(w1t + ((size_t)m * HID + t) * KP + k0);
            dst[0] = pk.q[0];
            dst[1] = pk.q[1];
        } else {
            // pad region k = 144..159: k=144 carries b1, rest zero.
            union { ushort us[8]; uint4 q; } pk;
#pragma unroll
            for (int j = 0; j < 8; ++j) pk.us[j] = 0;
            __hip_bfloat16 hb = __float2bfloat16(b1[(size_t)m * HID + t]);
            pk.us[0] = *(ushort*)&hb;
            uint4 z = {0u, 0u, 0u, 0u};
            uint4* dst = (uint4*)(w1t + ((size_t)m * HID + t) * KP + IN_DIM);
            dst[0] = pk.q;
            dst[1] = z;
        }
    } else {
        int c = (bid - 1280) * 256 + t;
        const int total = BATCH * (KF / 8);   // 24 chunks per row
        if (c >= total) return;
        int row = c / 24;
        int cc = c - row * 24;
        union { ushort us[8]; uint4 q; } pk;
#pragma unroll
        for (int j = 0; j < 8; ++j) {
            int k = cc * 8 + j;
            float v;
            if (k < NF)            v = f_t[(size_t)row * NF + k];
            else if (k < IN_DIM)   v = a_t[(size_t)row * NA + (k - NF)];
            else if (k == IN_DIM)  v = 1.0f;   // bias lane
            else                   v = 0.0f;
            __hip_bfloat16 h = __float2bfloat16(v);
            pk.us[j] = *(ushort*)&h;
        }
        int pc = cc ^ (row & 7);              // bijective within 24 chunks
        *(uint4*)(fab + (size_t)row * KF + pc * 8) = pk.q;
    }
}

// ---------------------------------------------------------------------------
// Fused grouped MLP — R7 schedule, 32x32x16 MFMA (half the MFMA instructions,
// ~17% fewer MFMA cycles vs 16x16x32; cuts total issue-port pressure).
// Grid 512 = 128 m (bid&127) x 4 slices of 1024 rows; 16 tiles of 64 rows.
// 256 thr = 4 waves; wave w owns hid cols [w*64, w*64+64) = 2 x 32-tiles.
// mfma(A=w1t frag, B=fa frag): D[row=hid][col=batch].
//  A/B frag (32x32x16): lane holds row/col (lane&31), k = (lane>>5)*8 + j.
//  C/D: col = lane&31, row = (reg&3) + 8*(reg>>2) + 4*(lane>>5).
__global__ __launch_bounds__(256, 2) void fused_mlp(
        const __hip_bfloat16* __restrict__ fab,
        const __hip_bfloat16* __restrict__ w1t,
        const float* __restrict__ W2,
        const float* __restrict__ b2,
        const float* __restrict__ f_t,
        float* __restrict__ out) {
    __shared__ __align__(16) __hip_bfloat16 Abuf[2][64 * KF];  // 2 x 24 KB
    __shared__ __align__(16) float partial[2][4][64];          // 2 KB

    const int bid = blockIdx.x;
    const int m     = bid & 127;     // same-m blocks 128 apart -> same XCD L2
    const int slice = bid >> 7;      // 0..3, 1024 rows each
    const int row_base = slice * 1024;
    const int t = threadIdx.x;
    const int w = t >> 6;            // wave = hid col group 0..3 (64 cols)
    const int lane = t & 63;
    const int l31 = lane & 31;
    const int h = lane >> 5;         // 0..1 (k-half / row-half selector)
    const int xr = (l31 & 7) << 4;   // byte XOR for swizzled LDS reads

    // ---- prologue: W1T frags (MFMA A operand): hid row = l31 (+32*hi2),
    // k = ks*16 + h*8 .. +8  -> b128 loads from w1t.
    bf16x8 bfrag[2][10];
#pragma unroll
    for (int hi2 = 0; hi2 < 2; ++hi2) {
        const int col = w * 64 + hi2 * 32 + l31;
        const __hip_bfloat16* wp = w1t + ((size_t)m * HID + col) * KP + h * 8;
#pragma unroll
        for (int ks = 0; ks < 10; ++ks)
            bfrag[hi2][ks] = *(const bf16x8*)(wp + ks * 16);
    }
    // w2v[hi2][reg]: reg = q*4+i -> hid row 8q + 4h + i  => 4x f32x4 per hi2
    f32x16 w2v[2];
#pragma unroll
    for (int hi2 = 0; hi2 < 2; ++hi2) {
        const float* wp2 = W2 + (size_t)m * HID + w * 64 + hi2 * 32 + 4 * h;
#pragma unroll
        for (int q = 0; q < 4; ++q) {
            f32x4 v = *(const f32x4*)(wp2 + 8 * q);
            w2v[hi2][q * 4 + 0] = v[0];
            w2v[hi2][q * 4 + 1] = v[1];
            w2v[hi2][q * 4 + 2] = v[2];
            w2v[hi2][q * 4 + 3] = v[3];
        }
    }
    const float b2v = b2[m];
    const f32x16 zc = (f32x16){0.f,0.f,0.f,0.f,0.f,0.f,0.f,0.f,
                               0.f,0.f,0.f,0.f,0.f,0.f,0.f,0.f};

    // ---- stage tile 0 (linear 24 KB copy; fab is pre-swizzled).
    {
        const char* src = (const char*)(fab + (size_t)row_base * KF);
        char* dst = (char*)&Abuf[0][0];
#pragma unroll
        for (int i = 0; i < 6; ++i)
            gl_lds16(src + (size_t)(t + i * 256) * 16, dst + (t + i * 256) * 16);
    }
    __syncthreads();

    for (int tile = 0; tile < 16; ++tile) {
        const int cur = tile & 1;
        const int r0 = row_base + tile * 64;

        // issue next tile's stage early (drained by this tile's barrier)
        if (tile < 15) {
            const char* src = (const char*)(fab + (size_t)(r0 + 64) * KF);
            char* dst = (char*)&Abuf[cur ^ 1][0];
#pragma unroll
            for (int i = 0; i < 6; ++i)
                gl_lds16(src + (size_t)(t + i * 256) * 16, dst + (t + i * 256) * 16);
        }
        // hoisted skip-connection gather (latency hidden under K-loop)
        float skipv = 0.0f;
        if (t < 64) skipv = f_t[(size_t)(r0 + t) * NF + m];

        f32x16 acc[2][2];   // [hi2][bj2]
        const char* ab = (const char*)&Abuf[cur][0];

        // ks = 0: C = zero vector (no per-tile acc zero-init VALU)
        {
            bf16x8 a[2];
#pragma unroll
            for (int bj2 = 0; bj2 < 2; ++bj2) {
                int row = bj2 * 32 + l31;
                int off = row * 384 + ((h * 16) ^ xr);
                a[bj2] = *(const bf16x8*)(ab + off);
            }
#pragma unroll
            for (int hi2 = 0; hi2 < 2; ++hi2)
#pragma unroll
                for (int bj2 = 0; bj2 < 2; ++bj2)
                    acc[hi2][bj2] = __builtin_amdgcn_mfma_f32_32x32x16_bf16(
                        bfrag[hi2][0], a[bj2], zc, 0, 0, 0);
        }
#pragma unroll
        for (int ks = 1; ks < 10; ++ks) {
            bf16x8 a[2];   // fa frag: batch = bj2*32 + l31, k = ks*16 + h*8
#pragma unroll
            for (int bj2 = 0; bj2 < 2; ++bj2) {
                int row = bj2 * 32 + l31;
                int off = row * 384 + ((ks * 32 + h * 16) ^ xr);
                a[bj2] = *(const bf16x8*)(ab + off);
            }
#pragma unroll
            for (int hi2 = 0; hi2 < 2; ++hi2)
#pragma unroll
                for (int bj2 = 0; bj2 < 2; ++bj2)
                    acc[hi2][bj2] = __builtin_amdgcn_mfma_f32_32x32x16_bf16(
                        bfrag[hi2][ks], a[bj2], acc[hi2][bj2], 0, 0, 0);
        }

        // ---- epilogue: relu(acc) * W2 (b1 folded into GEMM).
        // lane holds H[batch = bj2*32 + l31][hid rows per w2v mapping].
        float sarr[2];
#pragma unroll
        for (int bj2 = 0; bj2 < 2; ++bj2) {
            float sr0 = 0.f, sr1 = 0.f, sr2 = 0.f, sr3 = 0.f;
#pragma unroll
            for (int hi2 = 0; hi2 < 2; ++hi2)
#pragma unroll
                for (int q = 0; q < 4; ++q) {
                    float h0 = acc[hi2][bj2][q*4+0]; h0 = h0 > 0.f ? h0 : 0.f;
                    float h1 = acc[hi2][bj2][q*4+1]; h1 = h1 > 0.f ? h1 : 0.f;
                    float h2 = acc[hi2][bj2][q*4+2]; h2 = h2 > 0.f ? h2 : 0.f;
                    float h3 = acc[hi2][bj2][q*4+3]; h3 = h3 > 0.f ? h3 : 0.f;
                    sr0 = fmaf(h0, w2v[hi2][q*4+0], sr0);
                    sr1 = fmaf(h1, w2v[hi2][q*4+1], sr1);
                    sr2 = fmaf(h2, w2v[hi2][q*4+2], sr2);
                    sr3 = fmaf(h3, w2v[hi2][q*4+3], sr3);
                }
            float s = (sr0 + sr1) + (sr2 + sr3);
            // lanes l and l+32 hold complementary hid rows of the same batch col
            s += __shfl_xor(s, 32, 64);
            sarr[bj2] = s;
        }
        if (h == 0) {
            partial[cur][w][l31]      = sarr[0];
            partial[cur][w][32 + l31] = sarr[1];
        }

        __syncthreads();   // partial ready; stage(tile+1) drained; Abuf[cur] free
        if (t < 64) {
            float v = (partial[cur][0][t] + partial[cur][1][t])
                    + (partial[cur][2][t] + partial[cur][3][t])
                    + b2v + skipv;
            out[(size_t)(r0 + t) * NF + m] = v;
        }
    }
}

// ---------------------------------------------------------------------------
extern "C" void kernel_launch(void* const* d_in, const int* in_sizes, int n_in,
                              void* d_out, int out_size, void* d_ws, size_t ws_size,
                              hipStream_t stream) {
    const float* f_t = (const float*)d_in[0];
    const float* a_t = (const float*)d_in[1];
    const float* W1  = (const float*)d_in[2];
    const float* b1  = (const float*)d_in[3];
    const float* W2  = (const float*)d_in[4];
    const float* b2  = (const float*)d_in[5];
    float* out = (float*)d_out;

    // ws layout: w1t bf16 [128][256][160] (10.49 MB), fab bf16 [4096][192] (1.57 MB)
    __hip_bfloat16* w1t = (__hip_bfloat16*)d_ws;
    __hip_bfloat16* fab = (__hip_bfloat16*)((char*)d_ws + (size_t)NF * HID * KP * 2);

    // converts merged: 1280 w1t blocks + 384 fa blocks
    hipLaunchKernelGGL(convert_all, dim3(1664), dim3(256), 0, stream,
                       W1, b1, f_t, a_t, w1t, fab);
    hipLaunchKernelGGL(fused_mlp, dim3(512), dim3(256), 0, stream,
                       fab, w1t, W2, b2, f_t, out);
}

// Round 13
// 56.695 us; speedup vs baseline: 1.1482x; 1.0376x over previous
//
#include <hip/hip_runtime.h>
#include <hip/hip_bf16.h>

// Problem constants
#define BATCH   4096
#define NF      128    // n features == n models
#define NA      16
#define IN_DIM  144    // N_FEATURES + N_ACTIONS; K = 144 exactly (9 steps of 16)
#define KP      144    // w1t K (no pad; b1 folded via MFMA C-operand)
#define KF      192    // fab K padded so row = 384 B (swizzle-closed, 24 chunks)
#define HID     256

typedef __attribute__((ext_vector_type(8))) short bf16x8;
typedef __attribute__((ext_vector_type(4))) float f32x4;
typedef __attribute__((ext_vector_type(16))) float f32x16;
typedef unsigned int u32;

// async global->LDS, 16B per lane. LDS dest must be wave-uniform base + lane*16.
__device__ __forceinline__ void gl_lds16(const void* gsrc, void* ldst) {
    __builtin_amdgcn_global_load_lds(
        (const __attribute__((address_space(1))) u32*)gsrc,
        (__attribute__((address_space(3))) u32*)ldst, 16, 0, 0);
}

// staggered 3-bit swizzle key: rows sharing a key are not 8-aligned
__device__ __host__ __forceinline__ int swzkey(int row) {
    return (row + (row >> 3)) & 7;
}

// ---------------------------------------------------------------------------
// Merged convert kernel:
//   blocks [0, 1152):      W1 [128][144][256] fp32 -> w1t [128][256][144] bf16
//                          (transposed; no pad, b1 handled in fused prologue)
//   blocks [1152, 1536):   fa -> bf16 [4096][192], pre-swizzled:
//                          chunk cc of row stored at physical cc ^ swzkey(row)
__global__ void convert_all(const float* __restrict__ W1,
                            const float* __restrict__ f_t,
                            const float* __restrict__ a_t,
                            __hip_bfloat16* __restrict__ w1t,
                            __hip_bfloat16* __restrict__ fab) {
    const int bid = blockIdx.x;
    const int t = threadIdx.x;
    if (bid < 1152) {
        __shared__ float tile[16][HID];
        int m = bid / 9;
        int kc = bid - m * 9;
        int k0 = kc * 16;
#pragma unroll
        for (int i = 0; i < 16; ++i)
            tile[i][t] = W1[((size_t)m * IN_DIM + (k0 + i)) * HID + t];
        __syncthreads();
        union { ushort us[16]; uint4 q[2]; } pk;
#pragma unroll
        for (int i = 0; i < 16; ++i) {
            __hip_bfloat16 h = __float2bfloat16(tile[i][t]);
            pk.us[i] = *(ushort*)&h;
        }
        uint4* dst = (uint4*)(w1t + ((size_t)m * HID + t) * KP + k0);
        dst[0] = pk.q[0];
        dst[1] = pk.q[1];
    } else {
        int c = (bid - 1152) * 256 + t;
        const int total = BATCH * (KF / 8);   // 24 chunks per row
        if (c >= total) return;
        int row = c / 24;
        int cc = c - row * 24;
        union { ushort us[8]; uint4 q; } pk;
#pragma unroll
        for (int j = 0; j < 8; ++j) {
            int k = cc * 8 + j;
            float v;
            if (k < NF)            v = f_t[(size_t)row * NF + k];
            else if (k < IN_DIM)   v = a_t[(size_t)row * NA + (k - NF)];
            else                   v = 0.0f;
            __hip_bfloat16 h = __float2bfloat16(v);
            pk.us[j] = *(ushort*)&h;
        }
        int pc = cc ^ swzkey(row);            // bijective within 24 chunks
        *(uint4*)(fab + (size_t)row * KF + pc * 8) = pk.q;
    }
}

// ---------------------------------------------------------------------------
// Fused grouped MLP — 32x32x16 MFMA, K=144 (9 steps), b1 as C-operand init.
// Grid 512 = 128 m (bid&127) x 4 slices of 1024 rows; 16 tiles of 64 rows.
// 256 thr = 4 waves; wave w owns hid cols [w*64, w*64+64) = 2 x 32-tiles.
// mfma(A=w1t frag, B=fa frag): D[row=hid][col=batch].
//  A/B frag (32x32x16): lane holds row/col (lane&31), k = (lane>>5)*8 + j.
//  C/D: col = lane&31, row = (reg&3) + 8*(reg>>2) + 4*(lane>>5).
__global__ __launch_bounds__(256, 2) void fused_mlp(
        const __hip_bfloat16* __restrict__ fab,
        const __hip_bfloat16* __restrict__ w1t,
        const float* __restrict__ b1,
        const float* __restrict__ W2,
        const float* __restrict__ b2,
        const float* __restrict__ f_t,
        float* __restrict__ out) {
    __shared__ __align__(16) __hip_bfloat16 Abuf[2][64 * KF];  // 2 x 24 KB
    __shared__ __align__(16) float partial[2][4][64];          // 2 KB

    const int bid = blockIdx.x;
    const int m     = bid & 127;     // same-m blocks 128 apart -> same XCD L2
    const int slice = bid >> 7;      // 0..3, 1024 rows each
    const int row_base = slice * 1024;
    const int t = threadIdx.x;
    const int w = t >> 6;            // wave = hid col group 0..3 (64 cols)
    const int lane = t & 63;
    const int l31 = lane & 31;
    const int h = lane >> 5;         // 0..1 (k-half / row-half selector)
    // byte XOR keys for the two batch-row groups this lane reads:
    const int x0 = swzkey(l31) << 4;            // row = l31
    const int x1 = ((swzkey(l31) + 4) & 7) << 4; // row = 32 + l31

    // ---- prologue: W1T frags (MFMA A operand): hid = l31 (+32*hi2),
    // k = ks*16 + h*8 .. +8  -> b128 loads from w1t.
    bf16x8 bfrag[2][9];
#pragma unroll
    for (int hi2 = 0; hi2 < 2; ++hi2) {
        const int col = w * 64 + hi2 * 32 + l31;
        const __hip_bfloat16* wp = w1t + ((size_t)m * HID + col) * KP + h * 8;
#pragma unroll
        for (int ks = 0; ks < 9; ++ks)
            bfrag[hi2][ks] = *(const bf16x8*)(wp + ks * 16);
    }
    // w2v/b1v [hi2][reg]: reg = q*4+i -> hid row 8q + 4h + i
    f32x16 w2v[2], b1v[2];
#pragma unroll
    for (int hi2 = 0; hi2 < 2; ++hi2) {
        const float* wp2 = W2 + (size_t)m * HID + w * 64 + hi2 * 32 + 4 * h;
        const float* bp1 = b1 + (size_t)m * HID + w * 64 + hi2 * 32 + 4 * h;
#pragma unroll
        for (int q = 0; q < 4; ++q) {
            f32x4 v = *(const f32x4*)(wp2 + 8 * q);
            f32x4 bv = *(const f32x4*)(bp1 + 8 * q);
#pragma unroll
            for (int i = 0; i < 4; ++i) {
                w2v[hi2][q * 4 + i] = v[i];
                b1v[hi2][q * 4 + i] = bv[i];
            }
        }
    }
    const float b2v = b2[m];

    // ---- stage tile 0 (linear 24 KB copy; fab is pre-swizzled).
    {
        const char* src = (const char*)(fab + (size_t)row_base * KF);
        char* dst = (char*)&Abuf[0][0];
#pragma unroll
        for (int i = 0; i < 6; ++i)
            gl_lds16(src + (size_t)(t + i * 256) * 16, dst + (t + i * 256) * 16);
    }
    __syncthreads();

    for (int tile = 0; tile < 16; ++tile) {
        const int cur = tile & 1;
        const int r0 = row_base + tile * 64;

        // issue next tile's stage early (drained by this tile's barrier)
        if (tile < 15) {
            const char* src = (const char*)(fab + (size_t)(r0 + 64) * KF);
            char* dst = (char*)&Abuf[cur ^ 1][0];
#pragma unroll
            for (int i = 0; i < 6; ++i)
                gl_lds16(src + (size_t)(t + i * 256) * 16, dst + (t + i * 256) * 16);
        }
        // hoisted skip-connection gather (latency hidden under K-loop)
        float skipv = 0.0f;
        if (t < 64) skipv = f_t[(size_t)(r0 + t) * NF + m];

        f32x16 acc[2][2];   // [hi2][bj2]
        const char* ab = (const char*)&Abuf[cur][0];

        // ks = 0: C = b1 fragment (bias folded; no per-tile acc init VALU)
        {
            bf16x8 a[2];
            a[0] = *(const bf16x8*)(ab + l31 * 384 + ((h * 16) ^ x0));
            a[1] = *(const bf16x8*)(ab + (32 + l31) * 384 + ((h * 16) ^ x1));
#pragma unroll
            for (int hi2 = 0; hi2 < 2; ++hi2)
#pragma unroll
                for (int bj2 = 0; bj2 < 2; ++bj2)
                    acc[hi2][bj2] = __builtin_amdgcn_mfma_f32_32x32x16_bf16(
                        bfrag[hi2][0], a[bj2], b1v[hi2], 0, 0, 0);
        }
#pragma unroll
        for (int ks = 1; ks < 9; ++ks) {
            bf16x8 a[2];   // fa frag: batch = bj2*32 + l31, k = ks*16 + h*8
            int cb = ks * 32 + h * 16;   // chunk byte
            a[0] = *(const bf16x8*)(ab + l31 * 384 + (cb ^ x0));
            a[1] = *(const bf16x8*)(ab + (32 + l31) * 384 + (cb ^ x1));
#pragma unroll
            for (int hi2 = 0; hi2 < 2; ++hi2)
#pragma unroll
                for (int bj2 = 0; bj2 < 2; ++bj2)
                    acc[hi2][bj2] = __builtin_amdgcn_mfma_f32_32x32x16_bf16(
                        bfrag[hi2][ks], a[bj2], acc[hi2][bj2], 0, 0, 0);
        }

        // ---- epilogue: relu(acc) * W2 (b1 already in acc).
        float sarr[2];
#pragma unroll
        for (int bj2 = 0; bj2 < 2; ++bj2) {
            float sr0 = 0.f, sr1 = 0.f, sr2 = 0.f, sr3 = 0.f;
#pragma unroll
            for (int hi2 = 0; hi2 < 2; ++hi2)
#pragma unroll
                for (int q = 0; q < 4; ++q) {
                    float h0 = acc[hi2][bj2][q*4+0]; h0 = h0 > 0.f ? h0 : 0.f;
                    float h1 = acc[hi2][bj2][q*4+1]; h1 = h1 > 0.f ? h1 : 0.f;
                    float h2 = acc[hi2][bj2][q*4+2]; h2 = h2 > 0.f ? h2 : 0.f;
                    float h3 = acc[hi2][bj2][q*4+3]; h3 = h3 > 0.f ? h3 : 0.f;
                    sr0 = fmaf(h0, w2v[hi2][q*4+0], sr0);
                    sr1 = fmaf(h1, w2v[hi2][q*4+1], sr1);
                    sr2 = fmaf(h2, w2v[hi2][q*4+2], sr2);
                    sr3 = fmaf(h3, w2v[hi2][q*4+3], sr3);
                }
            float s = (sr0 + sr1) + (sr2 + sr3);
            // lanes l and l+32 hold complementary hid rows of the same batch col
            s += __shfl_xor(s, 32, 64);
            sarr[bj2] = s;
        }
        if (h == 0) {
            partial[cur][w][l31]      = sarr[0];
            partial[cur][w][32 + l31] = sarr[1];
        }

        __syncthreads();   // partial ready; stage(tile+1) drained; Abuf[cur] free
        if (t < 64) {
            float v = (partial[cur][0][t] + partial[cur][1][t])
                    + (partial[cur][2][t] + partial[cur][3][t])
                    + b2v + skipv;
            out[(size_t)(r0 + t) * NF + m] = v;
        }
    }
}

// ---------------------------------------------------------------------------
extern "C" void kernel_launch(void* const* d_in, const int* in_sizes, int n_in,
                              void* d_out, int out_size, void* d_ws, size_t ws_size,
                              hipStream_t stream) {
    const float* f_t = (const float*)d_in[0];
    const float* a_t = (const float*)d_in[1];
    const float* W1  = (const float*)d_in[2];
    const float* b1  = (const float*)d_in[3];
    const float* W2  = (const float*)d_in[4];
    const float* b2  = (const float*)d_in[5];
    float* out = (float*)d_out;

    // ws layout: w1t bf16 [128][256][144] (9.44 MB), fab bf16 [4096][192] (1.57 MB)
    __hip_bfloat16* w1t = (__hip_bfloat16*)d_ws;
    __hip_bfloat16* fab = (__hip_bfloat16*)((char*)d_ws + (size_t)NF * HID * KP * 2);

    // converts merged: 1152 w1t blocks + 384 fa blocks
    hipLaunchKernelGGL(convert_all, dim3(1536), dim3(256), 0, stream,
                       W1, f_t, a_t, w1t, fab);
    hipLaunchKernelGGL(fused_mlp, dim3(512), dim3(256), 0, stream,
                       fab, w1t, b1, W2, b2, f_t, out);
}